// Round 7
// baseline (231.166 us; speedup 1.0000x reference)
//
#include <hip/hip_runtime.h>
#include <hip/hip_bf16.h>

// AtomPoolingLayer: M=512, N=128 atoms, F=512, HID=128. fp32 in, fp32 out.
// out[m,f] = sum_n sigmoid(relu(h[m,n,:]@W1+b1)@W2+b2) * h[m,n,f]
//
// R13: R11 (206.7, 1 block/CU, exposed serial tails x2 generations) and
// R12 (212.0, 2 blocks/CU but +reduce_out launch, +part roundtrip, +2x B
// L2-traffic) each had half the answer. R13 = molecule/block (direct out,
// no partials) AND 2 blocks/CU: 256 threads, 64-row As, the molecule done
// in two 64-atom halves inside the block; phase-2 accumulates both halves
// into the same facc regs. As/w_s reused across halves (wave-local DS
// in-order makes read-then-overwrite safe without barriers). One barrier
// total. pack8 / MFMA addressing / epilogue / swizzle verbatim from
// verified rounds; only the final fp32 add association changes.

typedef unsigned short u16;
typedef unsigned int u32;
typedef __bf16 bf16x8 __attribute__((ext_vector_type(8)));
typedef float f32x4 __attribute__((ext_vector_type(4)));
typedef float f32x2 __attribute__((ext_vector_type(2)));
typedef u32 u32x4 __attribute__((ext_vector_type(4)));

#define M_MOL 512
#define N_ATOM 128
#define F_DIM 512
#define HID_DIM 128

static __device__ __forceinline__ u16 f2bf(float x) {
  u32 u = __float_as_uint(x);
  u32 r = (u + 0x7fffu + ((u >> 16) & 1u)) >> 16;  // RNE
  return (u16)r;
}
// repack two fp32x4 -> bf16x8 by truncation (|rel err| <= 2^-8)
static __device__ __forceinline__ bf16x8 pack8(u32x4 a, u32x4 b) {
  u32x4 r;
  r[0] = (a[0] >> 16) | (a[1] & 0xffff0000u);
  r[1] = (a[2] >> 16) | (a[3] & 0xffff0000u);
  r[2] = (b[0] >> 16) | (b[1] & 0xffff0000u);
  r[3] = (b[2] >> 16) | (b[3] & 0xffff0000u);
  return __builtin_bit_cast(bf16x8, r);
}

// ---- Kernel 1: W1 fp32 [F=512][HID=128] -> W1Tt bf16 [ks][hid][32] ----
__global__ __launch_bounds__(256) void transpose_w1(const float* __restrict__ W1,
                                                    u16* __restrict__ W1Tt) {
  __shared__ float tile[64][65];
  const int k0 = blockIdx.x * 64;
  const int n0 = blockIdx.y * 64;
  const int t = threadIdx.x;
  #pragma unroll
  for (int i = 0; i < 16; ++i) {
    const int lin = i * 256 + t;
    const int lr = lin >> 6, lc = lin & 63;
    tile[lc][lr] = W1[(size_t)(k0 + lr) * HID_DIM + (n0 + lc)];
  }
  __syncthreads();
  #pragma unroll
  for (int i = 0; i < 16; ++i) {
    const int lin = i * 256 + t;
    const int wr = lin >> 6, wc = lin & 63;   // wr: hid idx, wc: k idx
    const int k = k0 + wc;
    W1Tt[(size_t)(k >> 5) * (HID_DIM * 32) + (size_t)(n0 + wr) * 32 + (k & 31)] =
        f2bf(tile[wr][wc]);
  }
}

// ---- Kernel 2: one molecule per block; 256 thr; two 64-atom halves ----
__global__ __launch_bounds__(256, 2) void pool_mol2(
    const float* __restrict__ h, const u16* __restrict__ W1Tt,
    const float* __restrict__ b1, const float* __restrict__ W2,
    const float* __restrict__ b2, float* __restrict__ out) {
  // As: 64 rows x 512 bf16; 16-B chunk c of row r at phys chunk
  // (c&~7)|((c^r)&7) -> conflict-free (R6-verified). Reused per half.
  __shared__ u16 As[64 * F_DIM];          // 64 KiB
  __shared__ float red[4][F_DIM];         // 8 KiB
  __shared__ float w_s[64];               // 256 B

  const int m = blockIdx.x;
  const int tid = threadIdx.x;
  const int wv = tid >> 6;                // wave 0..3 -> local rows wv*16..+15
  const int lane = tid & 63;
  const int quad = lane >> 4;
  const int cl = lane & 15;

  const int lrow = wv * 16 + cl;          // local row in As (0..63)
  const u16* bg = W1Tt + cl * 32 + quad * 8;

  float facc[8] = {0.f, 0.f, 0.f, 0.f, 0.f, 0.f, 0.f, 0.f};

  #pragma unroll
  for (int hh = 0; hh < 2; ++hh) {
    // ---- A loads: lane owns global row hh*64+lrow, k = ks*32+quad*8..+7 ----
    const float* hr = h + ((size_t)m * N_ATOM + hh * 64 + lrow) * F_DIM;
    const u32x4* ap = (const u32x4*)hr + quad * 2;
    u32x4 a32[16][2];
    #pragma unroll
    for (int ks = 0; ks < 16; ++ks) {
      a32[ks][0] = ap[ks * 8];
      a32[ks][1] = ap[ks * 8 + 1];
    }

    // ---- B preload: tiles 0,1 (L1/L2-hot) ----
    u32x4 bf[3][8];                       // statically indexed under unroll
    #pragma unroll
    for (int p = 0; p < 2; ++p)
      #pragma unroll
      for (int t = 0; t < 8; ++t)
        bf[p][t] = *(const u32x4*)(bg + (size_t)p * (HID_DIM * 32) + t * 512);

    // ---- pack fp32->bf16 into ah + write-through to As ----
    bf16x8 ah[16];
    #pragma unroll
    for (int ks = 0; ks < 16; ++ks) {
      ah[ks] = pack8(a32[ks][0], a32[ks][1]);
      const int c = ks * 4 + quad;
      const int phys = (c & ~7) | ((c ^ cl) & 7);   // lrow&7 == cl&7
      *(bf16x8*)(As + lrow * F_DIM + phys * 8) = ah[ks];
    }

    // ---- Phase 1: T = h @ W1, MFMA 16x16x32; B 3-deep reg pipeline ----
    f32x4 acc[8];
    #pragma unroll
    for (int t = 0; t < 8; ++t) acc[t] = (f32x4){0.f, 0.f, 0.f, 0.f};

    #pragma unroll
    for (int ks = 0; ks < 16; ++ks) {
      if (ks < 14) {                      // prefetch tile ks+2
        #pragma unroll
        for (int t = 0; t < 8; ++t)
          bf[(ks + 2) % 3][t] =
              *(const u32x4*)(bg + (size_t)(ks + 2) * (HID_DIM * 32) + t * 512);
      }
      #pragma unroll
      for (int t = 0; t < 8; ++t)
        acc[t] = __builtin_amdgcn_mfma_f32_16x16x32_bf16(
            ah[ks], __builtin_bit_cast(bf16x8, bf[ks % 3][t]), acc[t], 0, 0, 0);
    }

    // ---- Epilogue: w = sigmoid(relu(T+b1)@W2 + b2) (verified) ----
    float psum[4] = {0.f, 0.f, 0.f, 0.f};
    #pragma unroll
    for (int t = 0; t < 8; ++t) {
      const int hid = t * 16 + cl;
      const float b1v = b1[hid];
      const float w2v = W2[hid];
      #pragma unroll
      for (int r = 0; r < 4; ++r) {
        float tv = fmaxf(acc[t][r] + b1v, 0.f);
        psum[r] = fmaf(tv, w2v, psum[r]);
      }
    }
    #pragma unroll
    for (int off = 1; off < 16; off <<= 1)
      #pragma unroll
      for (int r = 0; r < 4; ++r)
        psum[r] += __shfl_xor(psum[r], off, 64);
    if (cl == 0) {
      const float b2v = b2[0];
      #pragma unroll
      for (int r = 0; r < 4; ++r)
        w_s[wv * 16 + quad * 4 + r] = 1.f / (1.f + __expf(-(psum[r] + b2v)));
    }
    // wave-local fence: covers w_s write AND this wave's As write-through.
    asm volatile("s_waitcnt lgkmcnt(0)" ::: "memory");
    __builtin_amdgcn_sched_barrier(0);

    // ---- Phase 2: accumulate weighted sum over own 16 rows from As ----
    // (wave reads only its own rows; next half's overwrite is same-wave,
    //  in-order through the DS pipe -> no barrier needed)
    #pragma unroll 4
    for (int i = 0; i < 16; ++i) {
      const int r = wv * 16 + i;
      const float wn = w_s[r];
      const int phys = (lane & ~7) | ((lane ^ i) & 7);   // r&7 == i&7
      bf16x8 hv = *(const bf16x8*)(As + r * F_DIM + phys * 8);
      u32x4 uv = __builtin_bit_cast(u32x4, hv);
      #pragma unroll
      for (int j = 0; j < 4; ++j) {
        facc[2 * j]     = fmaf(wn, __uint_as_float(uv[j] << 16), facc[2 * j]);
        facc[2 * j + 1] = fmaf(wn, __uint_as_float(uv[j] & 0xffff0000u), facc[2 * j + 1]);
      }
    }
  }

  // ---- Cross-wave f-reduction (the ONLY barrier), direct out ----
  #pragma unroll
  for (int j = 0; j < 8; ++j) red[wv][lane * 8 + j] = facc[j];
  __syncthreads();

  {
    const int f = tid * 2;
    f32x2 o;
    o[0] = red[0][f] + red[1][f] + red[2][f] + red[3][f];
    o[1] = red[0][f + 1] + red[1][f + 1] + red[2][f + 1] + red[3][f + 1];
    *(f32x2*)(out + (size_t)m * F_DIM + f) = o;
  }
}

extern "C" void kernel_launch(void* const* d_in, const int* in_sizes, int n_in,
                              void* d_out, int out_size, void* d_ws, size_t ws_size,
                              hipStream_t stream) {
  const float* h  = (const float*)d_in[0];   // [512,128,512] fp32
  const float* W1 = (const float*)d_in[1];   // [512,128] fp32
  const float* b1 = (const float*)d_in[2];   // [128] fp32
  const float* W2 = (const float*)d_in[3];   // [128,1] fp32
  const float* b2 = (const float*)d_in[4];   // [1] fp32
  float* out = (float*)d_out;                // [512,512] fp32

  u16* W1Tt = (u16*)d_ws;                    // 128 KiB

  transpose_w1<<<dim3(8, 2), 256, 0, stream>>>(W1, W1Tt);
  pool_mol2<<<M_MOL, 256, 0, stream>>>(h, W1Tt, b1, W2, b2, out);
}

// Round 8
// 207.396 us; speedup vs baseline: 1.1146x; 1.1146x over previous
//
#include <hip/hip_runtime.h>
#include <hip/hip_bf16.h>

// AtomPoolingLayer: M=512, N=128 atoms, F=512, HID=128. fp32 in, fp32 out.
// out[m,f] = sum_n sigmoid(relu(h[m,n,:]@W1+b1)@W2+b2) * h[m,n,f]
//
// R14: restoration of R11 (session best, 206.7us). R12 (2 blocks/CU via
// halved blocks: 212.0) and R13 (2 blocks/CU via in-block halves: 231.2)
// both lost to R11 - the gate->reweight phases are true data dependencies;
// serializing them twice per block (R13) or paying an extra launch + part
// roundtrip + 2x B-traffic (R12) costs more than the occupancy overlap
// recovers. R11's shape: one molecule per 512-thr block, h global->VGPR
// once (A-frags), B streamed from L2-hot W1Tt via 3-deep register
// pipeline (no LDS staging, no conflicts), packed bf16 write-through to
// swizzled As feeding the conflict-free phase-2, single barrier, direct
// out (no partials). Remaining gap to the ~25us floor is latency-bound
// serial chain + ~155us fixed harness poison-fills (counter-verified:
// fills run 86% HBM peak; pool sits below the 76us top-5 cutoff).

typedef unsigned short u16;
typedef unsigned int u32;
typedef __bf16 bf16x8 __attribute__((ext_vector_type(8)));
typedef float f32x4 __attribute__((ext_vector_type(4)));
typedef u32 u32x4 __attribute__((ext_vector_type(4)));

#define M_MOL 512
#define N_ATOM 128
#define F_DIM 512
#define HID_DIM 128

static __device__ __forceinline__ u16 f2bf(float x) {
  u32 u = __float_as_uint(x);
  u32 r = (u + 0x7fffu + ((u >> 16) & 1u)) >> 16;  // RNE
  return (u16)r;
}
// repack two fp32x4 -> bf16x8 by truncation (|rel err| <= 2^-8)
static __device__ __forceinline__ bf16x8 pack8(u32x4 a, u32x4 b) {
  u32x4 r;
  r[0] = (a[0] >> 16) | (a[1] & 0xffff0000u);
  r[1] = (a[2] >> 16) | (a[3] & 0xffff0000u);
  r[2] = (b[0] >> 16) | (b[1] & 0xffff0000u);
  r[3] = (b[2] >> 16) | (b[3] & 0xffff0000u);
  return __builtin_bit_cast(bf16x8, r);
}

// ---- Kernel 1: W1 fp32 [F=512][HID=128] -> W1Tt bf16 [ks][hid][32] ----
// k-tile-contiguous: tile ks (32 k-elems x 128 hid = 8 KiB) is contiguous.
__global__ __launch_bounds__(256) void transpose_w1(const float* __restrict__ W1,
                                                    u16* __restrict__ W1Tt) {
  __shared__ float tile[64][65];
  const int k0 = blockIdx.x * 64;
  const int n0 = blockIdx.y * 64;
  const int t = threadIdx.x;
  #pragma unroll
  for (int i = 0; i < 16; ++i) {
    const int lin = i * 256 + t;
    const int lr = lin >> 6, lc = lin & 63;
    tile[lc][lr] = W1[(size_t)(k0 + lr) * HID_DIM + (n0 + lc)];
  }
  __syncthreads();
  #pragma unroll
  for (int i = 0; i < 16; ++i) {
    const int lin = i * 256 + t;
    const int wr = lin >> 6, wc = lin & 63;   // wr: hid idx, wc: k idx
    const int k = k0 + wc;
    W1Tt[(size_t)(k >> 5) * (HID_DIM * 32) + (size_t)(n0 + wr) * 32 + (k & 31)] =
        f2bf(tile[wr][wc]);
  }
}

// ---- Kernel 2: one molecule per block; 512 threads (8 waves x 16 rows) ----
__global__ __launch_bounds__(512, 2) void pool_mol(
    const float* __restrict__ h, const u16* __restrict__ W1Tt,
    const float* __restrict__ b1, const float* __restrict__ W2,
    const float* __restrict__ b2, float* __restrict__ out) {
  // As: h bf16, 128 rows x 512; 16-B chunk c of row r at phys chunk
  // (c&~7)|((c^r)&7)  -> conflict-free phase-2 reads (R6-verified layout).
  __shared__ u16 As[N_ATOM * F_DIM];      // 128 KiB
  __shared__ float red[8][F_DIM];         // 16 KiB
  __shared__ float w_s[N_ATOM];           // 512 B

  const int m = blockIdx.x;
  const int tid = threadIdx.x;
  const int wv = tid >> 6;                // wave 0..7 -> rows wv*16..+15
  const int lane = tid & 63;
  const int quad = lane >> 4;
  const int cl = lane & 15;

  // ---- A loads: lane (cl,quad) owns row, k = ks*32+quad*8..+7 ----
  // all 32 16-B loads issued up front -> deep HBM stream immediately
  const int row = wv * 16 + cl;
  const float* hr = h + ((size_t)m * N_ATOM + row) * F_DIM;
  const u32x4* ap = (const u32x4*)hr + quad * 2;
  u32x4 a32[16][2];
  #pragma unroll
  for (int ks = 0; ks < 16; ++ks) {
    a32[ks][0] = ap[ks * 8];
    a32[ks][1] = ap[ks * 8 + 1];
  }

  // ---- B preload: tiles 0,1 (L1/L2-hot; lane = W1Tt[ks][hid=t*16+cl][k=quad*8..]) ----
  const u16* bg = W1Tt + cl * 32 + quad * 8;
  u32x4 bf[3][8];                         // statically indexed under full unroll
  #pragma unroll
  for (int p = 0; p < 2; ++p)
    #pragma unroll
    for (int t = 0; t < 8; ++t)
      bf[p][t] = *(const u32x4*)(bg + (size_t)p * (HID_DIM * 32) + t * 512);

  // ---- pack fp32->bf16 into ah (MFMA A-frags) + write-through to As ----
  bf16x8 ah[16];
  #pragma unroll
  for (int ks = 0; ks < 16; ++ks) {
    ah[ks] = pack8(a32[ks][0], a32[ks][1]);
    const int c = ks * 4 + quad;
    const int phys = (c & ~7) | ((c ^ cl) & 7);   // row&7 == cl&7
    *(bf16x8*)(As + row * F_DIM + phys * 8) = ah[ks];
  }

  // ---- Phase 1: T = h @ W1, MFMA 16x16x32 bf16; B 3-deep reg pipeline ----
  f32x4 acc[8];
  #pragma unroll
  for (int t = 0; t < 8; ++t) acc[t] = (f32x4){0.f, 0.f, 0.f, 0.f};

  #pragma unroll
  for (int ks = 0; ks < 16; ++ks) {
    if (ks < 14) {                        // prefetch tile ks+2
      #pragma unroll
      for (int t = 0; t < 8; ++t)
        bf[(ks + 2) % 3][t] =
            *(const u32x4*)(bg + (size_t)(ks + 2) * (HID_DIM * 32) + t * 512);
    }
    #pragma unroll
    for (int t = 0; t < 8; ++t)
      acc[t] = __builtin_amdgcn_mfma_f32_16x16x32_bf16(
          ah[ks], __builtin_bit_cast(bf16x8, bf[ks % 3][t]), acc[t], 0, 0, 0);
  }

  // ---- Epilogue: w[row] = sigmoid(relu(T+b1)@W2 + b2)  (verified) ----
  float psum[4] = {0.f, 0.f, 0.f, 0.f};
  #pragma unroll
  for (int t = 0; t < 8; ++t) {
    const int hid = t * 16 + cl;
    const float b1v = b1[hid];
    const float w2v = W2[hid];
    #pragma unroll
    for (int r = 0; r < 4; ++r) {
      float tv = fmaxf(acc[t][r] + b1v, 0.f);
      psum[r] = fmaf(tv, w2v, psum[r]);
    }
  }
  #pragma unroll
  for (int off = 1; off < 16; off <<= 1)
    #pragma unroll
    for (int r = 0; r < 4; ++r)
      psum[r] += __shfl_xor(psum[r], off, 64);
  if (cl == 0) {
    const float b2v = b2[0];
    #pragma unroll
    for (int r = 0; r < 4; ++r)
      w_s[wv * 16 + quad * 4 + r] = 1.f / (1.f + __expf(-(psum[r] + b2v)));
  }
  // wave-local fence: covers w_s write AND this wave's As write-through.
  asm volatile("s_waitcnt lgkmcnt(0)" ::: "memory");
  __builtin_amdgcn_sched_barrier(0);

  // ---- Phase 2: weighted sum over own 16 rows from As (R6-verified) ----
  float facc[8] = {0.f, 0.f, 0.f, 0.f, 0.f, 0.f, 0.f, 0.f};
  #pragma unroll 4
  for (int i = 0; i < 16; ++i) {
    const int r = wv * 16 + i;
    const float wn = w_s[r];
    const int phys = (lane & ~7) | ((lane ^ i) & 7);   // r&7 == i&7
    bf16x8 hv = *(const bf16x8*)(As + r * F_DIM + phys * 8);
    u32x4 uv = __builtin_bit_cast(u32x4, hv);
    #pragma unroll
    for (int j = 0; j < 4; ++j) {
      facc[2 * j]     = fmaf(wn, __uint_as_float(uv[j] << 16), facc[2 * j]);
      facc[2 * j + 1] = fmaf(wn, __uint_as_float(uv[j] & 0xffff0000u), facc[2 * j + 1]);
    }
  }

  // ---- Cross-wave f-reduction (the ONLY barrier) ----
  #pragma unroll
  for (int j = 0; j < 8; ++j) red[wv][lane * 8 + j] = facc[j];
  __syncthreads();

  {
    const int f = tid;                    // 512 threads, 1 feature each
    float o = 0.f;
    #pragma unroll
    for (int w = 0; w < 8; ++w) o += red[w][f];
    out[(size_t)m * F_DIM + f] = o;
  }
}

extern "C" void kernel_launch(void* const* d_in, const int* in_sizes, int n_in,
                              void* d_out, int out_size, void* d_ws, size_t ws_size,
                              hipStream_t stream) {
  const float* h  = (const float*)d_in[0];   // [512,128,512] fp32
  const float* W1 = (const float*)d_in[1];   // [512,128] fp32
  const float* b1 = (const float*)d_in[2];   // [128] fp32
  const float* W2 = (const float*)d_in[3];   // [128,1] fp32
  const float* b2 = (const float*)d_in[4];   // [1] fp32
  float* out = (float*)d_out;                // [512,512] fp32

  u16* W1Tt = (u16*)d_ws;                    // 128 KiB

  transpose_w1<<<dim3(8, 2), 256, 0, stream>>>(W1, W1Tt);
  pool_mol<<<M_MOL, 512, 0, stream>>>(h, W1Tt, b1, W2, b2, out);
}